// Round 12
// baseline (501.014 us; speedup 1.0000x reference)
//
#include <hip/hip_runtime.h>
#include <math.h>

typedef unsigned long long u64;

static constexpr int S    = 771;   // NB_LABELS*MAX_DEPTH + EXTRA
static constexpr int Tn   = 128;
static constexpr int Bn   = 32;
static constexpr int BOSs = 0;
static constexpr int EOSs = 1;

static constexpr int JPAD  = 832;          // 13 * 64 state pad
static constexpr int JB    = 13;           // state-blocks per batch
static constexpr int ROWS  = 64;           // output rows per block (= lanes)
static constexpr int NQ    = 4;            // inner K-quarters (= waves)
static constexpr int SL    = JPAD / NQ;    // 208 i8 inner slice per thread
static constexpr int CH    = SL / 16;      // 13 x b128 per thread
static constexpr int EBLK  = NQ * CH * ROWS * 16;    // 53248 B per jblk
static constexpr int ETOT  = JB * EBLK;              // 692224 B
static constexpr int XSTR  = 224;          // padded stride (u64) per (parity,batch)
static constexpr int CAP   = 512;          // fast-poll rounds before fallback
static constexpr float CB  = 8.0f;         // normalizer headroom (drift bound)
static constexpr float C0V = 4.5f;         // fixed normalizer for t=0 publish

__device__ __forceinline__ float wave_max_bfly(float v) {   // result in ALL lanes
    #pragma unroll
    for (int off = 32; off > 0; off >>= 1) v = fmaxf(v, __shfl_xor(v, off));
    return v;
}
__device__ __forceinline__ float wave_sum_f(float v) {
    #pragma unroll
    for (int off = 32; off > 0; off >>= 1) v += __shfl_down(v, off);
    return v;
}

// ---- MALL-scope (agent atomic) ops: correct across XCDs (r4-r10 proven) ----
__device__ __forceinline__ u64 ald64(const u64* p) {
    return __hip_atomic_load((u64*)p, __ATOMIC_RELAXED, __HIP_MEMORY_SCOPE_AGENT);
}
__device__ __forceinline__ void ast64(u64* p, u64 v) {
    __hip_atomic_store(p, v, __ATOMIC_RELAXED, __HIP_MEMORY_SCOPE_AGENT);
}
// ---- XCD-local L2 ops: sc0 only (bypass L1, serve from this XCD's L2).
// Used ONLY as an opportunistic fast path; never load-bearing for progress.
__device__ __forceinline__ void ld2_l2(const u64* p0, const u64* p1,
                                       u64& a, u64& c) {
    asm volatile("global_load_dwordx2 %0, %2, off sc0\n\t"
                 "global_load_dwordx2 %1, %3, off sc0\n\t"
                 "s_waitcnt vmcnt(0)"
                 : "=&v"(a), "=&v"(c) : "v"(p0), "v"(p1) : "memory");
}
__device__ __forceinline__ void st_l2(u64* p, u64 v) {
    asm volatile("global_store_dwordx2 %0, %1, off sc0"
                 :: "v"(p), "v"(v) : "memory");
}
__device__ __forceinline__ u64 pack(unsigned tag, unsigned payload) {
    return ((u64)tag << 32) | (u64)payload;
}

// i8 x i8 + i32 dot (both operands in [0,127], so signed == unsigned)
#if __has_builtin(__builtin_amdgcn_sdot4)
__device__ __forceinline__ int dot4i(unsigned a, unsigned b, int c) {
    return __builtin_amdgcn_sdot4((int)a, (int)b, c, false);
}
#else
__device__ __forceinline__ int dot4i(unsigned a, unsigned b, int c) {
    c += (int)(a & 0xff)         * (int)(b & 0xff);
    c += (int)((a >> 8) & 0xff)  * (int)((b >> 8) & 0xff);
    c += (int)((a >> 16) & 0xff) * (int)((b >> 16) & 0xff);
    c += (int)((a >> 24) & 0xff) * (int)((b >> 24) & 0xff);
    return c;
}
#endif

// ---------------------------------------------------------------------------
// Prep: i8 exp-transition table (swizzled, layout unchanged since r8) +
// exp(trans[:,EOS]) f32 column.
// ---------------------------------------------------------------------------
extern "C" __global__ void build_tabs(const float* __restrict__ trans,
                                      unsigned char* __restrict__ eswz,
                                      float* __restrict__ eteos) {
    int idx = blockIdx.x * blockDim.x + threadIdx.x;
    if (idx < JPAD)
        eteos[idx] = (idx < S) ? __expf(trans[idx * S + EOSs]) : 0.f;
    if (idx >= ETOT) return;
    int e = idx & 15;
    int q = idx >> 4;
    int lane = q & 63;  q >>= 6;
    int kk = q % 13;
    int h  = q / 13;
    int w  = h & 3, jblk = h >> 2;
    int i = w * SL + kk * 16 + e;
    int j = jblk * ROWS + lane;
    float v = 0.f;
    if (i < S && j < S) v = 115.f * __expf(trans[i * S + j]);
    int q8 = (int)(v + 0.5f);
    if (q8 > 127) q8 = 127;
    eswz[idx] = (unsigned char)q8;
}

// dual publish (wave 0): 64 rows -> p8 = round(127*exp(alpha-C)) packed 4/u64
// (16 u64) + 1 u64 f32 chunk max, tagged (epoch+t). Written to BOTH the fast
// XCD-L2 mailbox (sc0 store) and the MALL mirror (agent atomic). The mirror
// makes consumer progress unconditional -- fast path is never load-bearing.
__device__ __forceinline__ void publish2(u64* WF, u64* WM, int jblk,
                                         unsigned tag, float af, float C,
                                         int lane) {
    float xf = fminf(127.f, 127.f * __expf(af - C));   // -inf/-1e9 -> 0
    int xi = (int)(xf + 0.5f);
    int b0 = __shfl(xi, (4 * lane) & 63);
    int b1 = __shfl(xi, (4 * lane + 1) & 63);
    int b2 = __shfl(xi, (4 * lane + 2) & 63);
    int b3 = __shfl(xi, (4 * lane + 3) & 63);
    unsigned payload = (unsigned)b0 | ((unsigned)b1 << 8)
                     | ((unsigned)b2 << 16) | ((unsigned)b3 << 24);
    float mc = wave_max_bfly(af);
    u64 vd = pack(tag, payload);
    u64 vm = pack(tag, __float_as_uint(mc));
    u64* bF = WF + 17 * jblk;
    u64* bM = WM + 17 * jblk;
    if (lane < 16)  { st_l2(bF + lane, vd); ast64(bM + lane, vd); }
    if (lane == 16) { st_l2(bF + 16, vm);   ast64(bM + 16, vm); }
}

// ---------------------------------------------------------------------------
// Forward algorithm, r12: hang-proof XCD-local exchange.
// r11 hung because its fast path was gated by an unverified HW-ID check.
// r12: no check -- every publish goes to fast mailbox (XCD-L2, sc0) AND MALL
// mirror (agent atomics). Each consumer wave spins on the fast mailbox for at
// most CAP rounds; on timeout it permanently falls back to polling the MALL
// mirror (r10-proven). The fast path proves itself by delivering data or is
// abandoned; progress never depends on it. Epoch-salted tags (s_memrealtime,
// odd; epoch+t != 0xAAAAAAAA since that needs t=169>127) defeat stale L2
// lines across graph replays. Swizzle puts each gang's 13 blocks on one XCD
// IF dispatch is round-robin (linear%8) -- a perf heuristic only.
// Everything else (i8 LDS E tile, per-wave strips, 1 barrier/step) = r10.
// ---------------------------------------------------------------------------
extern "C" __global__ __launch_bounds__(256, 2)
void crf_fwd(const float* __restrict__ em, const float* __restrict__ mask,
             const float* __restrict__ trans, const int* __restrict__ tags,
             const unsigned char* __restrict__ eswz,
             const float* __restrict__ eteos,
             u64* __restrict__ xbF, u64* __restrict__ xbM,
             unsigned* __restrict__ ctl, float* __restrict__ out) {
    const int l = blockIdx.x;                         // XCD-aware swizzle:
    const int b    = (l & 7) + 8 * ((l >> 3) / JB);   // gang's 13 blocks share
    const int jblk = (l >> 3) % JB;                   // linear_id % 8 == b % 8
    const int tid = threadIdx.x, lane = tid & 63, w = tid >> 6;
    const int j0 = jblk * ROWS;
    const int bw = (13 * w) / 4;             // first publisher of my K-quarter
    const int lo = 52 * w - 16 * bw;         // lane offset of my strip

    __shared__ __align__(16) unsigned char Elds[EBLK];  // 52 KB i8 E tile
    __shared__ __align__(16) unsigned pq[NQ][SL / 4];
    __shared__ int   part[2][NQ][ROWS];
    __shared__ float cshare;
    __shared__ float redv[4], redm[4];
    __shared__ unsigned sh_ep;

    const float KLOG  = __logf(115.f * 127.f);
    const float KL127 = __logf(127.f);

    // ---- one-time: stage this block's E tile ----
    {
        const unsigned char* gsrc = eswz + (size_t)jblk * EBLK;
        #pragma unroll
        for (int it = 0; it < EBLK / 4096; ++it)
            *(float4*)(Elds + it * 4096 + tid * 16) =
                *(const float4*)(gsrc + it * 4096 + tid * 16);
    }

    // ---- prologue: epoch agreement via MALL (hang-safe: poison is even) ----
    if (l == 0 && tid == 0) {
        u64 rt;
        asm volatile("s_memrealtime %0\n\ts_waitcnt lgkmcnt(0)" : "=s"(rt));
        unsigned ep = ((unsigned)rt & 0xffffff00u) | 1u;   // odd, low byte 1
        __hip_atomic_store(ctl, ep, __ATOMIC_RELAXED, __HIP_MEMORY_SCOPE_AGENT);
    }
    if (tid == 0) {
        unsigned ev;
        do {
            ev = __hip_atomic_load(ctl, __ATOMIC_RELAXED,
                                   __HIP_MEMORY_SCOPE_AGENT);
        } while (!(ev & 1u));
        sh_ep = ev;
    }
    __syncthreads();
    const unsigned epoch = sh_ep;

    // wave-0 per-lane state: alpha of own row + normalizer of consumed gen
    float af = -INFINITY, Cuse = C0V;
    if (w == 0) {
        int j = j0 + lane;
        if (j < S) af = trans[BOSs * S + j] + em[((size_t)b * Tn + 0) * S + j];
        publish2(xbF + ((size_t)0 * Bn + b) * XSTR,
                 xbM + ((size_t)0 * Bn + b) * XSTR, jblk, epoch, af, C0V, lane);
    }

    const bool pollmax = (w == 0) && (lane < JB);
    bool tryfast = true;   // per-wave adaptive flag (updated wave-uniformly)

    // ---- 127 sequential steps ----
    for (int t = 1; t < Tn; ++t) {
        const size_t ro = ((size_t)((t - 1) & 1) * Bn + b) * XSTR;
        const size_t wo = ((size_t)((t    ) & 1) * Bn + b) * XSTR;
        const u64* RF = xbF + ro;
        const u64* RM = xbM + ro;

        // epilogue operands independent of alpha: issue before the poll
        float emv = 0.f, mval = 0.f;
        if (w == 0) {
            const int j = j0 + lane;
            if (j < S) emv = em[((size_t)b * Tn + t) * S + j];
            mval = mask[b * Tn + t];
        }

        // ---- per-wave adaptive poll, tag = epoch + (t-1) ----
        const unsigned tg = epoch + (unsigned)(t - 1);
        const int doff = 17 * (bw + (lane >> 4)) + (lane & 15);
        const int moff = 17 * (pollmax ? lane : 0) + 16;
        u64 qd = 0, qm = 0;
        bool okd = false, okm = !pollmax;
        if (tryfast) {                 // phase A: XCD-L2 mailbox, bounded
            const u64* pdF = RF + doff;
            const u64* pmF = RF + moff;
            int spins = 0;
            for (;;) {
                u64 a, c;
                ld2_l2(pdF, pmF, a, c);
                if (!okd) { qd = a; okd = ((unsigned)(qd >> 32) == tg); }
                if (!okm) { qm = c; okm = ((unsigned)(qm >> 32) == tg); }
                if (!__any((!okd) | (!okm))) break;
                if (++spins >= CAP) { tryfast = false; break; }
            }
        }
        if (__any((!okd) | (!okm))) {  // phase B: MALL mirror, unconditional
            const u64* pdM = RM + doff;
            const u64* pmM = RM + moff;
            do {
                if (!okd) { qd = ald64(pdM); okd = ((unsigned)(qd >> 32) == tg); }
                if (!okm) { qm = ald64(pmM); okm = ((unsigned)(qm >> 32) == tg); }
            } while (__any((!okd) | (!okm)));
        }

        // ---- unpack own strip (same-wave write->read: DS order, no barrier)
        if (lane >= lo && lane < lo + 52) pq[w][lane - lo] = (unsigned)qd;

        // wave 0: next normalizer from the 13 chunk maxes
        float Cnew = 0.f;
        if (w == 0) {
            float mv = (lane < JB) ? __uint_as_float((unsigned)qm) : -INFINITY;
            Cnew = wave_max_bfly(mv) + CB;
        }

        // ---- dot: LDS i8 E (b128) x own strip (b128 broadcast) ----
        int acc = 0;
        const uint4* E4 = (const uint4*)Elds;
        const uint4* P4 = (const uint4*)pq[w];
        #pragma unroll
        for (int kk = 0; kk < CH; ++kk) {
            const uint4 ev = E4[(w * CH + kk) * 64 + lane];
            const uint4 pv = P4[kk];
            acc = dot4i(ev.x, pv.x, acc);
            acc = dot4i(ev.y, pv.y, acc);
            acc = dot4i(ev.z, pv.z, acc);
            acc = dot4i(ev.w, pv.w, acc);
        }
        part[t & 1][w][lane] = acc;
        __syncthreads();   // the ONLY per-step barrier

        // ---- epilogue (wave 0): combine, log, dual-publish gen t ----
        if (w == 0) {
            int s4 = part[t & 1][0][lane] + part[t & 1][1][lane]
                   + part[t & 1][2][lane] + part[t & 1][3][lane];
            float nv = Cuse - KLOG + __logf((float)s4) + emv;  // log(0) = -inf
            af = (mval > 0.f) ? nv : af;
            publish2(xbF + wo, xbM + wo, jblk, epoch + (unsigned)t,
                     af, Cnew, lane);
            if (lane == 0) cshare = Cnew;
            Cuse = Cnew;
        }
    }

    // ---- tail (block jblk==0 only): log_Z + gold score + output.
    // Polls the MALL mirror only (always correct; once per kernel). ----
    if (jblk == 0) {
        const u64* R = xbM + ((size_t)((Tn - 1) & 1) * Bn + b) * XSTR;
        const unsigned tg = epoch + (unsigned)(Tn - 1);
        const bool act = (tid < JB * 16);
        const u64* pp = R + 17 * (tid >> 4) + (tid & 15);
        u64 q = 0;
        bool ok = !act;
        while (true) {
            if (!ok) { q = ald64(pp); ok = ((unsigned)(q >> 32) == tg); }
            if (__syncthreads_and(ok)) break;
        }
        float lsum = 0.f;
        if (act) {
            unsigned pv = (unsigned)q;
            int base = 4 * tid;
            lsum = (float)(pv & 0xff)         * eteos[base]
                 + (float)((pv >> 8)  & 0xff) * eteos[base + 1]
                 + (float)((pv >> 16) & 0xff) * eteos[base + 2]
                 + (float)((pv >> 24) & 0xff) * eteos[base + 3];
        }
        // gold-path score (exact fp32: carries the -1e9 forbidden terms)
        float mk = 0.f, val = 0.f;
        if (tid < Tn) {
            mk = mask[b * Tn + tid];
            if (tid > 0) {
                int cur  = tags[b * Tn + tid];
                int prev = tags[b * Tn + tid - 1];
                val = (em[((size_t)b * Tn + tid) * S + cur]
                       + trans[prev * S + cur]) * mk;
            }
        }
        lsum = wave_sum_f(lsum);
        float vs = wave_sum_f(val);
        float ms = wave_sum_f(mk);
        if (lane == 0) { redv[w] = vs; redm[w] = ms; part[0][0][w] = 0; }
        if (lane == 1) part[1][0][w] = __float_as_int(lsum);
        __syncthreads();
        if (tid == 0) {
            float tot = __int_as_float(part[1][0][0]) + __int_as_float(part[1][0][1])
                      + __int_as_float(part[1][0][2]) + __int_as_float(part[1][0][3]);
            float logz = cshare - KL127 + __logf(tot);
            float msum = redm[0] + redm[1] + redm[2] + redm[3];
            int last   = (int)(msum + 0.5f) - 1;
            int first  = tags[b * Tn];
            int lastt  = tags[b * Tn + last];
            float score = redv[0] + redv[1] + redv[2] + redv[3]
                        + trans[BOSs * S + first]
                        + em[((size_t)b * Tn) * S + first]
                        + trans[lastt * S + EOSs];
            atomicAdd(out, -(score - logz));
        }
    }
}

extern "C" void kernel_launch(void* const* d_in, const int* in_sizes, int n_in,
                              void* d_out, int out_size, void* d_ws, size_t ws_size,
                              hipStream_t stream) {
    const float* em    = (const float*)d_in[0];
    const int*   tags  = (const int*)d_in[1];
    const float* mask  = (const float*)d_in[2];
    const float* trans = (const float*)d_in[3];
    float* out = (float*)d_out;

    char* ws = (char*)d_ws;
    size_t off = 0;
    unsigned char* eswz = (unsigned char*)(ws + off);
    off += (size_t)ETOT;
    off = (off + 255) & ~(size_t)255;
    float* eteos = (float*)(ws + off); off += JPAD * sizeof(float);
    off = (off + 255) & ~(size_t)255;
    u64* xbF = (u64*)(ws + off);       off += (size_t)2 * Bn * XSTR * sizeof(u64);
    off = (off + 255) & ~(size_t)255;
    u64* xbM = (u64*)(ws + off);       off += (size_t)2 * Bn * XSTR * sizeof(u64);
    off = (off + 255) & ~(size_t)255;
    unsigned* ctl = (unsigned*)(ws + off); off += 256;

    // ws re-poisoned 0xAA pre-launch: epoch slot and all mailbox tags reset
    (void)hipMemsetAsync(out, 0, sizeof(float), stream);

    build_tabs<<<(ETOT + 255) / 256, 256, 0, stream>>>(trans, eswz, eteos);
    crf_fwd<<<dim3(JB * Bn), 256, 0, stream>>>(em, mask, trans, tags, eswz,
                                               eteos, xbF, xbM, ctl, out);
}

// Round 13
// 435.381 us; speedup vs baseline: 1.1507x; 1.1507x over previous
//
#include <hip/hip_runtime.h>
#include <math.h>

typedef unsigned long long u64;

static constexpr int S    = 771;   // NB_LABELS*MAX_DEPTH + EXTRA
static constexpr int Tn   = 128;
static constexpr int Bn   = 32;
static constexpr int BOSs = 0;
static constexpr int EOSs = 1;

static constexpr int JPAD  = 832;          // 13 * 64 state pad
static constexpr int JB    = 13;           // state-blocks per batch
static constexpr int ROWS  = 64;           // output rows per block (= lanes)
static constexpr int NQ    = 4;            // inner K-quarters (= waves)
static constexpr int SL    = JPAD / NQ;    // 208 i8 inner slice per thread
static constexpr int CH    = SL / 16;      // 13 x b128 per thread
static constexpr int EBLK  = NQ * CH * ROWS * 16;    // 53248 B per jblk
static constexpr int ETOT  = JB * EBLK;              // 692224 B
static constexpr int NPUB  = 16;           // u64 per publisher (max embedded)
static constexpr int XSTR  = 224;          // stride (u64) per (parity,batch)
static constexpr unsigned TAGB = 0x5A00u;  // tag16 = 0x5A00|t; poison=0xAAAA
static constexpr float CB  = 8.0f;         // normalizer headroom (drift bound)
static constexpr float C0V = 4.5f;         // fixed normalizer for t=0 publish

__device__ __forceinline__ float wave_max_bfly(float v) {   // result in ALL lanes
    #pragma unroll
    for (int off = 32; off > 0; off >>= 1) v = fmaxf(v, __shfl_xor(v, off));
    return v;
}
__device__ __forceinline__ float wave_sum_f(float v) {
    #pragma unroll
    for (int off = 32; off > 0; off >>= 1) v += __shfl_down(v, off);
    return v;
}

union HU16 { _Float16 h; unsigned short u; };

// MALL-scope (agent atomic) exchange: the r4-r10 replay-proven protocol.
__device__ __forceinline__ u64 ald64(const u64* p) {
    return __hip_atomic_load((u64*)p, __ATOMIC_RELAXED, __HIP_MEMORY_SCOPE_AGENT);
}
__device__ __forceinline__ void ast64(u64* p, u64 v) {
    __hip_atomic_store(p, v, __ATOMIC_RELAXED, __HIP_MEMORY_SCOPE_AGENT);
}

// i8 x i8 + i32 dot (both operands in [0,127], so signed == unsigned)
#if __has_builtin(__builtin_amdgcn_sdot4)
__device__ __forceinline__ int dot4i(unsigned a, unsigned b, int c) {
    return __builtin_amdgcn_sdot4((int)a, (int)b, c, false);
}
#else
__device__ __forceinline__ int dot4i(unsigned a, unsigned b, int c) {
    c += (int)(a & 0xff)         * (int)(b & 0xff);
    c += (int)((a >> 8) & 0xff)  * (int)((b >> 8) & 0xff);
    c += (int)((a >> 16) & 0xff) * (int)((b >> 16) & 0xff);
    c += (int)((a >> 24) & 0xff) * (int)((b >> 24) & 0xff);
    return c;
}
#endif

// ---------------------------------------------------------------------------
// Prep: i8 exp-transition table (swizzled, layout unchanged since r8) +
// exp(trans[:,EOS]) f32 column.
// eswz[jblk][q][kk][lane][16] = round(115*exp(trans[i][j])) in [0,127],
//   i = q*208 + kk*16 + e (inner), j = jblk*64 + lane (output row).
// ---------------------------------------------------------------------------
extern "C" __global__ void build_tabs(const float* __restrict__ trans,
                                      unsigned char* __restrict__ eswz,
                                      float* __restrict__ eteos) {
    int idx = blockIdx.x * blockDim.x + threadIdx.x;
    if (idx < JPAD)
        eteos[idx] = (idx < S) ? __expf(trans[idx * S + EOSs]) : 0.f;
    if (idx >= ETOT) return;
    int e = idx & 15;
    int q = idx >> 4;
    int lane = q & 63;  q >>= 6;
    int kk = q % 13;
    int h  = q / 13;
    int w  = h & 3, jblk = h >> 2;
    int i = w * SL + kk * 16 + e;
    int j = jblk * ROWS + lane;
    float v = 0.f;
    if (i < S && j < S) v = 115.f * __expf(trans[i * S + j]);
    int q8 = (int)(v + 0.5f);
    if (q8 > 127) q8 = 127;
    eswz[idx] = (unsigned char)q8;
}

// publish (one wave): 64 rows -> 16 tagged u64, each carrying
// [tag16 | chunkmax_f16 | 4 x p8], p8 = round(127*exp(alpha-C)).
// Max rides in EVERY data word -> consumers need no second poll target.
__device__ __forceinline__ void publish(u64* base, unsigned tg, float af,
                                        float C, int lane) {
    float xf = fminf(127.f, 127.f * __expf(af - C));   // -inf/-1e9 -> 0
    int xi = (int)(xf + 0.5f);
    int c0 = __shfl(xi, (4 * lane) & 63);
    int c1 = __shfl(xi, (4 * lane + 1) & 63);
    int c2 = __shfl(xi, (4 * lane + 2) & 63);
    int c3 = __shfl(xi, (4 * lane + 3) & 63);
    unsigned payload = (unsigned)c0 | ((unsigned)c1 << 8)
                     | ((unsigned)c2 << 16) | ((unsigned)c3 << 24);
    float mc = wave_max_bfly(af);
    HU16 hh; hh.h = (_Float16)mc;     // f16 chunk max (used only via fmax)
    u64 v = ((u64)tg << 48) | ((u64)hh.u << 32) | (u64)payload;
    if (lane < NPUB) ast64(base + lane, v);
}

// ---------------------------------------------------------------------------
// Forward algorithm, r13: TWO-BATCH PHASE-INTERLEAVED PIPELINE.
// r10 counters: ~6240 cy/step = MALL RT (~4300, exposed) + compute (~1900).
// r12 falsified beating the RT with XCD-local sc0 (L2-channel contention).
// r13 hides it instead: grid 13x16=208 blocks (1/CU), each block runs two
// batches per step in alternating phases. While batch A's publish crosses
// the MALL, the block computes batch B. Phase = per-wave poll (ONE u64/lane,
// tag16 match; max embedded) -> strip to own LDS quarter (same-wave, no
// barrier) -> i8 dot4 vs LDS E -> barrier -> epilogue wave (0 for A, 1 for
// B) combines, logs, publishes. part/wmax double-buffered by phase so waves
// 1-3 enter phase B while wave 0 finishes A's epilogue. Buffer-reuse safety
// per batch = r8 transitivity argument, phases independent.
// ---------------------------------------------------------------------------
extern "C" __global__ __launch_bounds__(256, 2)
void crf_fwd(const float* __restrict__ em, const float* __restrict__ mask,
             const float* __restrict__ trans, const int* __restrict__ tags,
             const unsigned char* __restrict__ eswz,
             const float* __restrict__ eteos,
             u64* __restrict__ xb, float* __restrict__ out) {
    const int jblk = blockIdx.x;
    const int b0 = blockIdx.y * 2, b1 = b0 + 1;
    const int tid = threadIdx.x, lane = tid & 63, w = tid >> 6;
    const int j0 = jblk * ROWS;
    const int bw = (13 * w) / 4;             // first publisher of my K-quarter
    const int lo = 52 * w - 16 * bw;         // lane offset of my strip

    __shared__ __align__(16) unsigned char Elds[EBLK];  // 52 KB i8 E tile
    __shared__ __align__(16) unsigned pq[2][NQ][52];    // per-phase wave strips
    __shared__ int   part[2][NQ][ROWS];
    __shared__ float wmax[2][NQ];
    __shared__ float csh[2];
    __shared__ float lz[2][4];
    __shared__ float redv[4], redm[4];

    const float KLOG  = __logf(115.f * 127.f);
    const float KL127 = __logf(127.f);

    // ---- one-time: stage this block's E tile (13 x 4KB linear copy) ----
    {
        const unsigned char* gsrc = eswz + (size_t)jblk * EBLK;
        #pragma unroll
        for (int it = 0; it < EBLK / 4096; ++it)
            *(float4*)(Elds + it * 4096 + tid * 16) =
                *(const float4*)(gsrc + it * 4096 + tid * 16);
    }

    // epilogue waves 0/1 own batches b0/b1: alpha of row j0+lane + normalizer
    const int myb = (w == 1) ? b1 : b0;
    float af = -INFINITY, Cuse = C0V;
    if (w < 2) {
        int j = j0 + lane;
        if (j < S) af = trans[BOSs * S + j] + em[((size_t)myb * Tn + 0) * S + j];
        publish(xb + ((size_t)0 * Bn + myb) * XSTR + NPUB * jblk,
                TAGB | 0u, af, C0V, lane);
    }

    // ---- 127 sequential steps, 2 phases each ----
    for (int t = 1; t < Tn; ++t) {
        const unsigned tgp = TAGB | (unsigned)(t - 1);
        const unsigned tgc = TAGB | (unsigned)t;

        // epilogue operands (waves 0/1 -> own batch), issued before any poll
        float emv = 0.f, mval = 0.f;
        if (w < 2) {
            const int j = j0 + lane;
            if (j < S) emv = em[((size_t)myb * Tn + t) * S + j];
            mval = mask[myb * Tn + t];
        }

        // ================= phase A : batch b0 =================
        {
            const u64* R = xb + ((size_t)((t - 1) & 1) * Bn + b0) * XSTR;
            const u64* pd = R + NPUB * (bw + (lane >> 4)) + (lane & 15);
            u64 q = 0; bool ok = false;
            do {
                if (!ok) { q = ald64(pd); ok = ((unsigned)(q >> 48) == tgp); }
            } while (__any(!ok));
            if (lane >= lo && lane < lo + 52) pq[0][w][lane - lo] = (unsigned)q;
            HU16 hm; hm.u = (unsigned short)(q >> 32);
            float wm = wave_max_bfly((float)hm.h);
            if (lane == 0) wmax[0][w] = wm;

            int acc = 0;
            const uint4* E4 = (const uint4*)Elds;
            const uint4* P4 = (const uint4*)pq[0][w];
            #pragma unroll
            for (int kk = 0; kk < CH; ++kk) {
                const uint4 ev = E4[(w * CH + kk) * 64 + lane];
                const uint4 pv = P4[kk];
                acc = dot4i(ev.x, pv.x, acc); acc = dot4i(ev.y, pv.y, acc);
                acc = dot4i(ev.z, pv.z, acc); acc = dot4i(ev.w, pv.w, acc);
            }
            part[0][w][lane] = acc;
            __syncthreads();
            if (w == 0) {   // waves 1-3 already head into phase B poll
                int s4 = part[0][0][lane] + part[0][1][lane]
                       + part[0][2][lane] + part[0][3][lane];
                float Cnew = fmaxf(fmaxf(wmax[0][0], wmax[0][1]),
                                   fmaxf(wmax[0][2], wmax[0][3])) + CB;
                float nv = Cuse - KLOG + __logf((float)s4) + emv;
                af = (mval > 0.f) ? nv : af;
                publish(xb + ((size_t)(t & 1) * Bn + b0) * XSTR + NPUB * jblk,
                        tgc, af, Cnew, lane);
                Cuse = Cnew;
            }
        }

        // ================= phase B : batch b1 =================
        {
            const u64* R = xb + ((size_t)((t - 1) & 1) * Bn + b1) * XSTR;
            const u64* pd = R + NPUB * (bw + (lane >> 4)) + (lane & 15);
            u64 q = 0; bool ok = false;
            do {
                if (!ok) { q = ald64(pd); ok = ((unsigned)(q >> 48) == tgp); }
            } while (__any(!ok));
            if (lane >= lo && lane < lo + 52) pq[1][w][lane - lo] = (unsigned)q;
            HU16 hm; hm.u = (unsigned short)(q >> 32);
            float wm = wave_max_bfly((float)hm.h);
            if (lane == 0) wmax[1][w] = wm;

            int acc = 0;
            const uint4* E4 = (const uint4*)Elds;
            const uint4* P4 = (const uint4*)pq[1][w];
            #pragma unroll
            for (int kk = 0; kk < CH; ++kk) {
                const uint4 ev = E4[(w * CH + kk) * 64 + lane];
                const uint4 pv = P4[kk];
                acc = dot4i(ev.x, pv.x, acc); acc = dot4i(ev.y, pv.y, acc);
                acc = dot4i(ev.z, pv.z, acc); acc = dot4i(ev.w, pv.w, acc);
            }
            part[1][w][lane] = acc;
            __syncthreads();
            if (w == 1) {   // other waves proceed to t+1 phase A
                int s4 = part[1][0][lane] + part[1][1][lane]
                       + part[1][2][lane] + part[1][3][lane];
                float Cnew = fmaxf(fmaxf(wmax[1][0], wmax[1][1]),
                                   fmaxf(wmax[1][2], wmax[1][3])) + CB;
                float nv = Cuse - KLOG + __logf((float)s4) + emv;
                af = (mval > 0.f) ? nv : af;
                publish(xb + ((size_t)(t & 1) * Bn + b1) * XSTR + NPUB * jblk,
                        tgc, af, Cnew, lane);
                Cuse = Cnew;
            }
        }
    }

    // ---- tail (blocks jblk==0): log_Z + gold scores for both batches ----
    if (jblk == 0) {
        if (w < 2 && lane == 0) csh[w] = Cuse;   // C of gen-127 publish
        const unsigned tgf = TAGB | (unsigned)(Tn - 1);
        const u64* RA = xb + ((size_t)((Tn - 1) & 1) * Bn + b0) * XSTR;
        const u64* RB = xb + ((size_t)((Tn - 1) & 1) * Bn + b1) * XSTR;
        const bool actp = (tid < JB * NPUB);     // 208 slots
        u64 qa = 0, qb = 0;
        bool oka = !actp, okb = !actp;
        while (true) {
            if (!oka) { qa = ald64(RA + tid); oka = ((unsigned)(qa >> 48) == tgf); }
            if (!okb) { qb = ald64(RB + tid); okb = ((unsigned)(qb >> 48) == tgf); }
            if (__syncthreads_and(oka & okb)) break;
        }
        float lA = 0.f, lB = 0.f;
        if (actp) {
            unsigned pa = (unsigned)qa, pb = (unsigned)qb;
            int base = 4 * tid;
            lA = (float)(pa & 0xff)         * eteos[base]
               + (float)((pa >> 8)  & 0xff) * eteos[base + 1]
               + (float)((pa >> 16) & 0xff) * eteos[base + 2]
               + (float)((pa >> 24) & 0xff) * eteos[base + 3];
            lB = (float)(pb & 0xff)         * eteos[base]
               + (float)((pb >> 8)  & 0xff) * eteos[base + 1]
               + (float)((pb >> 16) & 0xff) * eteos[base + 2]
               + (float)((pb >> 24) & 0xff) * eteos[base + 3];
        }
        lA = wave_sum_f(lA);
        lB = wave_sum_f(lB);
        if (lane == 0) { lz[0][w] = lA; lz[1][w] = lB; }

        // gold scores: threads 0-127 = batch A pos tid; 128-255 = batch B
        int pos = tid & 127;
        int gb  = (tid < 128) ? b0 : b1;
        float mk = mask[gb * Tn + pos];
        float val = 0.f;
        if (pos > 0) {
            int cur  = tags[gb * Tn + pos];
            int prev = tags[gb * Tn + pos - 1];
            val = (em[((size_t)gb * Tn + pos) * S + cur]
                   + trans[prev * S + cur]) * mk;
        }
        float vs = wave_sum_f(val);
        float ms = wave_sum_f(mk);
        if (lane == 0) { redv[w] = vs; redm[w] = ms; }
        __syncthreads();
        if (tid == 0) {
            float totA = lz[0][0] + lz[0][1] + lz[0][2] + lz[0][3];
            float totB = lz[1][0] + lz[1][1] + lz[1][2] + lz[1][3];
            float logzA = csh[0] - KL127 + __logf(totA);
            float logzB = csh[1] - KL127 + __logf(totB);
            float msA = redm[0] + redm[1], msB = redm[2] + redm[3];
            int lastA = (int)(msA + 0.5f) - 1, lastB = (int)(msB + 0.5f) - 1;
            int fA = tags[b0 * Tn], fB = tags[b1 * Tn];
            int lTA = tags[b0 * Tn + lastA], lTB = tags[b1 * Tn + lastB];
            float scoreA = redv[0] + redv[1] + trans[BOSs * S + fA]
                         + em[((size_t)b0 * Tn) * S + fA] + trans[lTA * S + EOSs];
            float scoreB = redv[2] + redv[3] + trans[BOSs * S + fB]
                         + em[((size_t)b1 * Tn) * S + fB] + trans[lTB * S + EOSs];
            atomicAdd(out, -(scoreA - logzA) - (scoreB - logzB));
        }
    }
}

extern "C" void kernel_launch(void* const* d_in, const int* in_sizes, int n_in,
                              void* d_out, int out_size, void* d_ws, size_t ws_size,
                              hipStream_t stream) {
    const float* em    = (const float*)d_in[0];
    const int*   tags  = (const int*)d_in[1];
    const float* mask  = (const float*)d_in[2];
    const float* trans = (const float*)d_in[3];
    float* out = (float*)d_out;

    char* ws = (char*)d_ws;
    size_t off = 0;
    unsigned char* eswz = (unsigned char*)(ws + off);
    off += (size_t)ETOT;
    off = (off + 255) & ~(size_t)255;
    float* eteos = (float*)(ws + off); off += JPAD * sizeof(float);
    off = (off + 255) & ~(size_t)255;
    u64* xb = (u64*)(ws + off);        off += (size_t)2 * Bn * XSTR * sizeof(u64);

    // ws re-poisoned 0xAA pre-launch: poison tag16 = 0xAAAA never matches
    // TAGB|t (high byte 0x5A) -> stale mailbox words can't be consumed.
    (void)hipMemsetAsync(out, 0, sizeof(float), stream);

    build_tabs<<<(ETOT + 255) / 256, 256, 0, stream>>>(trans, eswz, eteos);
    crf_fwd<<<dim3(JB, Bn / 2), 256, 0, stream>>>(em, mask, trans, tags, eswz,
                                                  eteos, xb, out);
}